// Round 2
// baseline (4522.286 us; speedup 1.0000x reference)
//
#include <hip/hip_runtime.h>
#include <math.h>

#define NB 128      // B
#define NT 12       // T
#define NNODE 207   // N
#define NF 14       // F
#define NH 128      // H
#define ROWS (NB*NNODE)      // 26496
#define BTN (NB*NT*NNODE)    // 317952
#define G3 (3*NH)            // 384

__device__ __forceinline__ float sigf(float x){ return 1.0f/(1.0f+__expf(-x)); }

__global__ __launch_bounds__(256) void k_sentinel(float* __restrict__ out, int n){
  int i = blockIdx.x*256 + threadIdx.x;
  if (i < n) out[i] = 12345.0f;
}

// emb = tanh(state * fc_w + fc_b)   (B,N,16)
__global__ __launch_bounds__(256) void k_emb(const float* __restrict__ x,
    const float* __restrict__ w, const float* __restrict__ b, float* __restrict__ emb){
  int idx = blockIdx.x*256 + threadIdx.x;
  if (idx >= ROWS*16) return;
  int j = idx & 15, row = idx >> 4;
  int bb = row / NNODE, n = row % NNODE;
  float s = x[((bb*NT + (NT-1))*NNODE + n)*NF];
  emb[idx] = tanhf(s*w[j] + b[j]);
}

// per (b,n) row: A_dyn row, top-10 (tie->lowest idx), sparse softmax, blend with A_phys
__global__ __launch_bounds__(256) void k_adj(const float* __restrict__ emb,
    const float* __restrict__ Aph, const float* __restrict__ alp,
    float* __restrict__ Abuf, float* __restrict__ rsum){
  __shared__ float en[16];
  __shared__ float dv[NNODE];
  __shared__ int kept[NNODE];
  __shared__ float rv[256];
  __shared__ int ri[256];
  int row = blockIdx.x, tid = threadIdx.x;
  int bb = row / NNODE, n = row % NNODE;
  if (tid < 16) en[tid] = emb[row*16 + tid];
  __syncthreads();
  if (tid < NNODE){
    const float* em = emb + (bb*NNODE + tid)*16;
    float d = 0.f;
    #pragma unroll
    for (int j=0;j<16;++j) d += en[j]*em[j];
    dv[tid] = d > 0.f ? d : 0.f;
    kept[tid] = 0;
  }
  __syncthreads();
  float vmax = 0.f;
  for (int it=0; it<10; ++it){
    float v = -1.f; int id = 1<<20;
    if (tid < NNODE && !kept[tid]){ v = dv[tid]; id = tid; }
    rv[tid] = v; ri[tid] = id;
    __syncthreads();
    for (int s=128; s>0; s>>=1){
      if (tid < s){
        float v2 = rv[tid+s]; int i2 = ri[tid+s];
        if (v2 > rv[tid] || (v2 == rv[tid] && i2 < ri[tid])){ rv[tid]=v2; ri[tid]=i2; }
      }
      __syncthreads();
    }
    if (it == 0) vmax = rv[0];          // global max (relu'd, >=0)
    if (tid == 0) kept[ri[0]] = 1;
    __syncthreads();
  }
  float part = 0.f;
  if (tid < NNODE){
    float v = kept[tid] ? dv[tid] : 0.f;
    part = __expf(v - vmax);
  }
  rv[tid] = part; __syncthreads();
  for (int s=128;s>0;s>>=1){ if (tid<s) rv[tid]+=rv[tid+s]; __syncthreads(); }
  float ssum = rv[0];
  __syncthreads();
  float a = sigf(alp[0]);
  float Av = 0.f;
  if (tid < NNODE){
    Av = a*Aph[n*NNODE + tid] + (1.f-a)*(part/ssum);
    Abuf[(size_t)row*NNODE + tid] = Av;
  }
  rv[tid] = Av; __syncthreads();
  for (int s=128;s>0;s>>=1){ if (tid<s) rv[tid]+=rv[tid+s]; __syncthreads(); }
  if (tid == 0) rsum[row] = rv[0];
}

__global__ __launch_bounds__(256) void k_lam(const float* __restrict__ rsum, float* __restrict__ lam){
  __shared__ float rv[256];
  int b = blockIdx.x, tid = threadIdx.x;
  rv[tid] = (tid < NNODE) ? rsum[b*NNODE+tid] : -1e30f;
  __syncthreads();
  for (int s=128;s>0;s>>=1){ if (tid<s) rv[tid]=fmaxf(rv[tid],rv[tid+s]); __syncthreads(); }
  if (tid==0) lam[b] = fmaxf(rv[0], 1.0f);
}

__global__ __launch_bounds__(256) void k_lap(float* __restrict__ Abuf, const float* __restrict__ lam){
  int idx = blockIdx.x*256 + threadIdx.x;
  if (idx >= NB*NNODE*NNODE) return;
  int b = idx / (NNODE*NNODE);
  int rem = idx % (NNODE*NNODE);
  int n = rem / NNODE, m = rem % NNODE;
  Abuf[idx] = 2.f*Abuf[idx]/lam[b] - (n==m ? 1.f : 0.f);
}

// causal conv(3) + GLU -> t_feat (B,T,N,32)
__global__ __launch_bounds__(256) void k_tcn(const float* __restrict__ x,
    const float* __restrict__ w, const float* __restrict__ bcn, float* __restrict__ tfeat){
  int idx = blockIdx.x*256 + threadIdx.x;
  if (idx >= BTN*32) return;
  int o = idx & 31; int r = idx >> 5;
  int n = r % NNODE, bt = r / NNODE, t = bt % NT, b = bt / NT;
  float t0 = (t>=2)? x[((size_t)(b*NT+t-2)*NNODE+n)*NF] : 0.f;
  float t1 = (t>=1)? x[((size_t)(b*NT+t-1)*NNODE+n)*NF] : 0.f;
  float t2 = x[((size_t)(b*NT+t)*NNODE+n)*NF];
  float P = bcn[o]    + w[o*3]*t0       + w[o*3+1]*t1       + w[o*3+2]*t2;
  float Q = bcn[o+32] + w[(o+32)*3]*t0  + w[(o+32)*3+1]*t1  + w[(o+32)*3+2]*t2;
  tfeat[(size_t)r*32 + o] = P * sigf(Q);
}

// RB = tfeat@th1 -> P2 ; RC = tfeat@th2 -> P1     layout (B, N, T*32)
__global__ __launch_bounds__(256) void k_thetaBC(const float* __restrict__ tfeat,
    const float* __restrict__ theta, float* __restrict__ P2, float* __restrict__ P1){
  __shared__ float thB[32][33], thC[32][33];
  __shared__ float tf[8][32];
  int tid = threadIdx.x;
  for (int i=tid; i<1024; i+=256){
    int f = i >> 5, o = i & 31;
    thB[o][f] = theta[1024+f*32+o]; thC[o][f] = theta[2048+f*32+o];
  }
  int rl = tid >> 5, o = tid & 31;
  int r = blockIdx.x*8 + rl;
  tf[rl][o] = tfeat[(size_t)r*32 + o];
  __syncthreads();
  float aB=0.f, aC=0.f;
  #pragma unroll
  for (int f=0; f<32; ++f){
    float t = tf[rl][f];
    aB += t*thB[o][f]; aC += t*thC[o][f];
  }
  int n = r % NNODE, bt = r / NNODE, t = bt % NT, b = bt / NT;
  size_t outi = (size_t)(b*NNODE+n)*G3 + t*32 + o;
  P2[outi]=aB; P1[outi]=aC;
}

// RA = tfeat@(th0-th2) -> P1
__global__ __launch_bounds__(256) void k_thetaA(const float* __restrict__ tfeat,
    const float* __restrict__ theta, float* __restrict__ P1){
  __shared__ float thA[32][33];
  __shared__ float tf[8][32];
  int tid = threadIdx.x;
  for (int i=tid; i<1024; i+=256){
    int f = i >> 5, o = i & 31;
    thA[o][f] = theta[f*32+o] - theta[2048+f*32+o];
  }
  int rl = tid >> 5, o = tid & 31;
  int r = blockIdx.x*8 + rl;
  tf[rl][o] = tfeat[(size_t)r*32 + o];
  __syncthreads();
  float aA=0.f;
  #pragma unroll
  for (int f=0; f<32; ++f) aA += tf[rl][f]*thA[o][f];
  int n = r % NNODE, bt = r / NNODE, t = bt % NT, b = bt / NT;
  P1[(size_t)(b*NNODE+n)*G3 + t*32 + o] = aA;
}

// batched C[b] = alpha*(A[b]@X[b]) + beta*Y[b] (optional relu). A:(M,K) row-major, X:(K,N)
__global__ __launch_bounds__(256) void gemm_nn(const float* __restrict__ Ab,
    const float* __restrict__ Xb, const float* __restrict__ Yb, float* __restrict__ Cb,
    int M, int N, int K, int sA, int sX, int sY, int sC,
    float alphaV, float betaV, int do_relu){
  __shared__ float As[16][65];
  __shared__ float Xs[16][65];
  int b = blockIdx.z;
  const float* A = Ab + (size_t)b*sA;
  const float* X = Xb + (size_t)b*sX;
  const float* Y = Yb + (size_t)b*sY;
  float* C = Cb + (size_t)b*sC;
  int n0 = blockIdx.x*64, m0 = blockIdx.y*64;
  int tid = threadIdx.x, tx = tid & 15, ty = tid >> 4;
  float acc[4][4] = {};
  int l_m = tid >> 2, l_k4 = (tid & 3)*4;
  for (int k0=0; k0<K; k0+=16){
    #pragma unroll
    for (int j=0;j<4;++j){
      int k = k0 + l_k4 + j; int m = m0 + l_m;
      As[l_k4+j][l_m] = (m<M && k<K) ? A[(size_t)m*K + k] : 0.f;
    }
    #pragma unroll
    for (int j=0;j<4;++j){
      int idx = tid + j*256; int kk = idx >> 6, nn = idx & 63;
      int k = k0 + kk, n = n0 + nn;
      Xs[kk][nn] = (k<K && n<N) ? X[(size_t)k*N + n] : 0.f;
    }
    __syncthreads();
    #pragma unroll
    for (int kk=0; kk<16; ++kk){
      float av[4], bv[4];
      #pragma unroll
      for (int i=0;i<4;++i) av[i]=As[kk][ty*4+i];
      #pragma unroll
      for (int j=0;j<4;++j) bv[j]=Xs[kk][tx*4+j];
      #pragma unroll
      for (int i=0;i<4;++i)
        #pragma unroll
        for (int j=0;j<4;++j) acc[i][j] += av[i]*bv[j];
    }
    __syncthreads();
  }
  #pragma unroll
  for (int i=0;i<4;++i){
    int m = m0 + ty*4 + i; if (m >= M) continue;
    #pragma unroll
    for (int j=0;j<4;++j){
      int n = n0 + tx*4 + j; if (n >= N) continue;
      float v = alphaV*acc[i][j];
      if (betaV != 0.f) v += betaV*Y[(size_t)m*N + n];
      if (do_relu) v = v > 0.f ? v : 0.f;
      C[(size_t)m*N + n] = v;
    }
  }
}

// C = A(M,K) @ W(N,K)^T + bias   (x @ weight.T)
__global__ __launch_bounds__(256) void gemm_nt(const float* __restrict__ A, int lda,
    const float* __restrict__ W, int ldw, const float* __restrict__ bias,
    float* __restrict__ C, int M, int N, int K){
  __shared__ float As[16][65];
  __shared__ float Ws[16][65];
  int n0 = blockIdx.x*64, m0 = blockIdx.y*64;
  int tid = threadIdx.x, tx = tid & 15, ty = tid >> 4;
  float acc[4][4] = {};
  int l_r = tid >> 2, l_k4 = (tid & 3)*4;
  for (int k0=0; k0<K; k0+=16){
    #pragma unroll
    for (int j=0;j<4;++j){
      int k = k0 + l_k4 + j;
      int m = m0 + l_r;
      As[l_k4+j][l_r] = (m<M && k<K) ? A[(size_t)m*lda + k] : 0.f;
      int n = n0 + l_r;
      Ws[l_k4+j][l_r] = (n<N && k<K) ? W[(size_t)n*ldw + k] : 0.f;
    }
    __syncthreads();
    #pragma unroll
    for (int kk=0; kk<16; ++kk){
      float av[4], bv[4];
      #pragma unroll
      for (int i=0;i<4;++i) av[i]=As[kk][ty*4+i];
      #pragma unroll
      for (int j=0;j<4;++j) bv[j]=Ws[kk][tx*4+j];
      #pragma unroll
      for (int i=0;i<4;++i)
        #pragma unroll
        for (int j=0;j<4;++j) acc[i][j] += av[i]*bv[j];
    }
    __syncthreads();
  }
  #pragma unroll
  for (int i=0;i<4;++i){
    int m = m0 + ty*4 + i; if (m >= M) continue;
    #pragma unroll
    for (int j=0;j<4;++j){
      int n = n0 + tx*4 + j; if (n >= N) continue;
      C[(size_t)m*N + n] = acc[i][j] + bias[n];
    }
  }
}

// fusion, attn gate, write z in (tau, i, 65) layout + ctx + pred0
__global__ __launch_bounds__(256) void k_zbuild(const float* __restrict__ x,
    const float* __restrict__ S, const float* __restrict__ cw, const float* __restrict__ cb,
    const float* __restrict__ aw, const float* __restrict__ ab,
    float* __restrict__ ztm, float* __restrict__ ctx, float* __restrict__ pred0){
  int tid = threadIdx.x;
  int rl = tid >> 6, l = tid & 63;
  int r = blockIdx.x*4 + rl;
  int n = r % NNODE, bt = r / NNODE, t = bt % NT, b = bt / NT;
  const float* xr = x + (size_t)r*NF;
  float fu, fu64 = 0.f;
  if (l == 0){
    fu = xr[0];
    float s_ = cb[31];
    #pragma unroll
    for (int f=0; f<13; ++f) s_ += xr[1+f]*cw[31*13+f];
    fu64 = s_ > 0.f ? s_ : 0.f;
  } else if (l < 33){
    fu = S[(size_t)(b*NNODE+n)*G3 + t*32 + (l-1)];
  } else {
    int o = l - 33;
    float s_ = cb[o];
    #pragma unroll
    for (int f=0; f<13; ++f) s_ += xr[1+f]*cw[o*13+f];
    fu = s_ > 0.f ? s_ : 0.f;
  }
  float part = fu*aw[l] + (l==0 ? fu64*aw[64] : 0.f);
  #pragma unroll
  for (int off=32; off; off>>=1) part += __shfl_down(part, off, 64);
  part = __shfl(part, 0, 64);
  float attn = sigf(part + ab[0]);
  int i_ = r / NT, tau = r % NT;          // scrambled reshape (B*N, T, 65)
  float* zr = ztm + ((size_t)tau*ROWS + i_)*65;
  zr[l] = fu*attn;
  if (l == 0) zr[64] = fu64*attn;
  if (t == NT-1){
    if (l >= 33) ctx[(size_t)(b*NNODE+n)*32 + (l-33)] = fu;
    if (l == 0){ ctx[(size_t)(b*NNODE+n)*32 + 31] = fu64; pred0[b*NNODE+n] = xr[0]; }
  }
}

__global__ __launch_bounds__(256) void k_gru(const float* __restrict__ gX,
    const float* __restrict__ gH, float* __restrict__ h){
  int idx = blockIdx.x*256 + threadIdx.x;
  if (idx >= ROWS*NH) return;
  int i = idx >> 7, j = idx & 127;
  const float* gx = gX + (size_t)i*G3;
  const float* gh = gH + (size_t)i*G3;
  float r  = sigf(gx[j] + gh[j]);
  float z  = sigf(gx[NH+j] + gh[NH+j]);
  float nn = tanhf(gx[2*NH+j] + r*gh[2*NH+j]);
  h[idx] = (1.f - z)*nn + z*h[idx];
}

__global__ __launch_bounds__(128) void k_dec(const float* __restrict__ ctxGX,
    const float* __restrict__ gH, const float* __restrict__ wih,
    const float* __restrict__ ow, const float* __restrict__ ob,
    float* __restrict__ h, float* __restrict__ pred, float* __restrict__ preds_out){
  __shared__ float ssum[2];
  int i = blockIdx.x, j = threadIdx.x;
  float p = pred[i];
  const float* gx = ctxGX + (size_t)i*G3;
  const float* gh = gH + (size_t)i*G3;
  float r  = sigf(gx[j]      + p*wih[j*33]        + gh[j]);
  float z  = sigf(gx[NH+j]   + p*wih[(NH+j)*33]   + gh[NH+j]);
  float nn = tanhf(gx[2*NH+j] + p*wih[(2*NH+j)*33] + r*gh[2*NH+j]);
  float h2 = (1.f - z)*nn + z*h[(size_t)i*NH + j];
  h[(size_t)i*NH + j] = h2;
  float part = h2*ow[j];
  #pragma unroll
  for (int off=32; off; off>>=1) part += __shfl_down(part, off, 64);
  if ((j & 63) == 0) ssum[j >> 6] = part;
  __syncthreads();
  if (j == 0){
    float pn = ssum[0] + ssum[1] + ob[0];
    pred[i] = pn; preds_out[i] = pn;
  }
}

__global__ __launch_bounds__(256) void k_out(const float* __restrict__ preds, float* __restrict__ out){
  int idx = blockIdx.x*256 + threadIdx.x;
  if (idx >= NT*ROWS) return;
  int n = idx % NNODE;
  int t2 = idx / NNODE;
  int hor = t2 % NT;
  int b = t2 / NT;
  out[idx] = preds[(size_t)hor*ROWS + b*NNODE + n];
}

extern "C" void kernel_launch(void* const* d_in, const int* in_sizes, int n_in,
                              void* d_out, int out_size, void* d_ws, size_t ws_size,
                              hipStream_t stream){
  const float* x     = (const float*)d_in[0];
  const float* Aph   = (const float*)d_in[1];
  const float* fcw   = (const float*)d_in[2];
  const float* fcb   = (const float*)d_in[3];
  const float* alp   = (const float*)d_in[4];
  const float* cw    = (const float*)d_in[5];
  const float* cb    = (const float*)d_in[6];
  const float* tw    = (const float*)d_in[7];
  const float* tb    = (const float*)d_in[8];
  const float* theta = (const float*)d_in[9];
  const float* aw    = (const float*)d_in[10];
  const float* ab    = (const float*)d_in[11];
  const float* ewih  = (const float*)d_in[12];
  const float* ewhh  = (const float*)d_in[13];
  const float* ebih  = (const float*)d_in[14];
  const float* ebhh  = (const float*)d_in[15];
  const float* dwih  = (const float*)d_in[16];
  const float* dwhh  = (const float*)d_in[17];
  const float* dbih  = (const float*)d_in[18];
  const float* dbhh  = (const float*)d_in[19];
  const float* ow    = (const float*)d_in[20];
  const float* ob    = (const float*)d_in[21];
  float* out = (float*)d_out;

  // ---- workspace overlay plan (sizes in floats) ----
  const size_t SZ_H    = (size_t)ROWS*NH;        // 3,391,488
  const size_t SZ_CTX  = (size_t)ROWS*32;        //   847,872
  const size_t SZ_PRED = (size_t)ROWS;           //    26,496
  const size_t SZ_PREDS= (size_t)NT*ROWS;        //   317,952
  const size_t SZ_G    = (size_t)ROWS*G3;        // 10,174,464
  const size_t SZ_ABUF = (size_t)NB*NNODE*NNODE; //  5,484,672
  const size_t SZ_EMB  = (size_t)ROWS*16;        //   423,936
  const size_t SZ_Z    = (size_t)NT*ROWS*65;     // 20,666,880

  float* w = (float*)d_ws;
  size_t off = 0;
  auto alloc = [&](size_t nfl){ float* p = w + off; off += nfl; return p; };
  float* h     = alloc(SZ_H);
  float* ctx   = alloc(SZ_CTX);
  float* pred  = alloc(SZ_PRED);
  float* preds = alloc(SZ_PREDS);
  float* gH    = alloc(SZ_G);
  float* Abuf  = alloc(SZ_ABUF);
  float* emb   = alloc(SZ_EMB);
  float* rsum  = alloc(SZ_PRED);
  float* lam   = alloc((size_t)NB);
  float* Sslot = alloc(SZ_G);      // t_feat -> S -> gX -> ctxGX
  float* Zzone = alloc(SZ_Z);      // P1 | P2 | pad ; later z (tau,i,65)
  float* P1 = Zzone;
  float* P2 = Zzone + SZ_G;
  (void)n_in; (void)in_sizes; (void)out_size;

  if (ws_size < off*sizeof(float)){    // tripwire: workspace too small
    k_sentinel<<<(out_size+255)/256, 256, 0, stream>>>(out, out_size);
    return;
  }

  float* tfeat = Sslot;
  k_emb<<<(ROWS*16)/256, 256, 0, stream>>>(x, fcw, fcb, emb);
  k_adj<<<ROWS, 256, 0, stream>>>(emb, Aph, alp, Abuf, rsum);
  k_lam<<<NB, 256, 0, stream>>>(rsum, lam);
  k_lap<<<(NB*NNODE*NNODE + 255)/256, 256, 0, stream>>>(Abuf, lam);
  k_tcn<<<(BTN*32)/256, 256, 0, stream>>>(x, tw, tb, tfeat);
  k_thetaBC<<<BTN/8, 256, 0, stream>>>(tfeat, theta, P2, P1);
  // P2 <- 2*(L @ P1) + P2        (W = R1 + 2 L R2)
  gemm_nn<<<dim3(G3/64, (NNODE+63)/64, NB), 256, 0, stream>>>(Abuf, P1, P2, P2,
      NNODE, G3, NNODE, NNODE*NNODE, NNODE*G3, NNODE*G3, NNODE*G3, 2.f, 1.f, 0);
  k_thetaA<<<BTN/8, 256, 0, stream>>>(tfeat, theta, P1);
  // Sslot <- relu((L @ P2) + P1)  (s = relu(R0 - R2 + L W)); tfeat dead now
  gemm_nn<<<dim3(G3/64, (NNODE+63)/64, NB), 256, 0, stream>>>(Abuf, P2, P1, Sslot,
      NNODE, G3, NNODE, NNODE*NNODE, NNODE*G3, NNODE*G3, NNODE*G3, 1.f, 1.f, 1);
  k_zbuild<<<BTN/4, 256, 0, stream>>>(x, Sslot, cw, cb, aw, ab, Zzone, ctx, pred);
  hipMemsetAsync(h, 0, SZ_H*sizeof(float), stream);

  float* gX = Sslot;   // S dead after zbuild
  for (int t=0; t<NT; ++t){
    gemm_nt<<<dim3(G3/64, ROWS/64), 256, 0, stream>>>(Zzone + (size_t)t*ROWS*65, 65,
        ewih, 65, ebih, gX, ROWS, G3, 65);
    gemm_nt<<<dim3(G3/64, ROWS/64), 256, 0, stream>>>(h, NH, ewhh, NH, ebhh, gH,
        ROWS, G3, NH);
    k_gru<<<(ROWS*NH)/256, 256, 0, stream>>>(gX, gH, h);
  }
  float* ctxGX = Sslot;  // gX dead after encoder
  gemm_nt<<<dim3(G3/64, ROWS/64), 256, 0, stream>>>(ctx, 32, dwih+1, 33, dbih,
      ctxGX, ROWS, G3, 32);
  for (int s=0; s<NT; ++s){
    gemm_nt<<<dim3(G3/64, ROWS/64), 256, 0, stream>>>(h, NH, dwhh, NH, dbhh, gH,
        ROWS, G3, NH);
    k_dec<<<ROWS, 128, 0, stream>>>(ctxGX, gH, dwih, ow, ob, h, pred,
        preds + (size_t)s*ROWS);
  }
  k_out<<<(NT*ROWS)/256, 256, 0, stream>>>(preds, out);
}

// Round 3
// 2688.687 us; speedup vs baseline: 1.6820x; 1.6820x over previous
//
#include <hip/hip_runtime.h>
#include <math.h>

#define NB 128      // B
#define NT 12       // T
#define NNODE 207   // N
#define NF 14       // F
#define NH 128      // H
#define ROWS (NB*NNODE)      // 26496
#define BTN (NB*NT*NNODE)    // 317952
#define G3 (3*NH)            // 384

__device__ __forceinline__ float sigf(float x){ return 1.0f/(1.0f+__expf(-x)); }

__global__ __launch_bounds__(256) void k_sentinel(float* __restrict__ out, int n){
  int i = blockIdx.x*256 + threadIdx.x;
  if (i < n) out[i] = 12345.0f;
}

// emb = tanh(state * fc_w + fc_b)   (B,N,16)
__global__ __launch_bounds__(256) void k_emb(const float* __restrict__ x,
    const float* __restrict__ w, const float* __restrict__ b, float* __restrict__ emb){
  int idx = blockIdx.x*256 + threadIdx.x;
  if (idx >= ROWS*16) return;
  int j = idx & 15, row = idx >> 4;
  int bb = row / NNODE, n = row % NNODE;
  float s = x[((bb*NT + (NT-1))*NNODE + n)*NF];
  emb[idx] = tanhf(s*w[j] + b[j]);
}

// wave-per-row: A_dyn row, top-10 (tie->lowest idx), sparse softmax, blend, rowsum
__global__ __launch_bounds__(256) void k_adj(const float* __restrict__ emb,
    const float* __restrict__ Aph, const float* __restrict__ alp,
    float* __restrict__ Abuf, float* __restrict__ rsum){
  int wid = threadIdx.x >> 6, lane = threadIdx.x & 63;
  int row = blockIdx.x*4 + wid;
  int bb = row / NNODE, n = row % NNODE;
  const float4* er = (const float4*)(emb + (size_t)row*16);
  float4 e0 = er[0], e1 = er[1], e2 = er[2], e3 = er[3];
  float d[4];
  #pragma unroll
  for (int q=0;q<4;++q){
    int m = lane + q*64;
    float dd = -1.f;
    if (m < NNODE){
      const float4* em = (const float4*)(emb + (size_t)(bb*NNODE+m)*16);
      float4 m0 = em[0], m1 = em[1], m2 = em[2], m3 = em[3];
      dd = e0.x*m0.x + e0.y*m0.y + e0.z*m0.z + e0.w*m0.w
         + e1.x*m1.x + e1.y*m1.y + e1.z*m1.z + e1.w*m1.w
         + e2.x*m2.x + e2.y*m2.y + e2.z*m2.z + e2.w*m2.w
         + e3.x*m3.x + e3.y*m3.y + e3.z*m3.z + e3.w*m3.w;
      dd = dd > 0.f ? dd : 0.f;
    }
    d[q] = dd;
  }
  int km = 0;
  float vmax = 0.f;
  for (int it=0; it<10; ++it){
    float v = -1.f; int mi = 1<<20;
    #pragma unroll
    for (int q=0;q<4;++q){
      if (d[q] >= 0.f && !((km>>q)&1) && d[q] > v){ v = d[q]; mi = lane + q*64; }
    }
    #pragma unroll
    for (int off=1; off<64; off<<=1){
      float v2 = __shfl_xor(v, off, 64);
      int  i2 = __shfl_xor(mi, off, 64);
      if (v2 > v || (v2 == v && i2 < mi)){ v = v2; mi = i2; }
    }
    if (it == 0) vmax = v;
    if ((mi & 63) == lane) km |= 1 << (mi >> 6);
  }
  float a = sigf(alp[0]);
  float eneg = __expf(-vmax);
  float p[4]; float ps = 0.f;
  #pragma unroll
  for (int q=0;q<4;++q){
    p[q] = 0.f;
    if (d[q] >= 0.f) p[q] = ((km>>q)&1) ? __expf(d[q]-vmax) : eneg;
    ps += p[q];
  }
  #pragma unroll
  for (int off=1; off<64; off<<=1) ps += __shfl_xor(ps, off, 64);
  float inv = (1.f - a)/ps;
  float rs = 0.f;
  #pragma unroll
  for (int q=0;q<4;++q){
    int m = lane + q*64;
    if (m < NNODE){
      float Av = a*Aph[n*NNODE + m] + p[q]*inv;
      Abuf[(size_t)row*NNODE + m] = Av;
      rs += Av;
    }
  }
  #pragma unroll
  for (int off=1; off<64; off<<=1) rs += __shfl_xor(rs, off, 64);
  if (lane == 0) rsum[row] = rs;
}

__global__ __launch_bounds__(256) void k_lam(const float* __restrict__ rsum, float* __restrict__ lam){
  __shared__ float rv[256];
  int b = blockIdx.x, tid = threadIdx.x;
  rv[tid] = (tid < NNODE) ? rsum[b*NNODE+tid] : -1e30f;
  __syncthreads();
  for (int s=128;s>0;s>>=1){ if (tid<s) rv[tid]=fmaxf(rv[tid],rv[tid+s]); __syncthreads(); }
  if (tid==0) lam[b] = fmaxf(rv[0], 1.0f);
}

__global__ __launch_bounds__(256) void k_lap(float* __restrict__ Abuf, const float* __restrict__ lam){
  int idx = blockIdx.x*256 + threadIdx.x;
  if (idx >= NB*NNODE*NNODE) return;
  int b = idx / (NNODE*NNODE);
  int rem = idx % (NNODE*NNODE);
  int n = rem / NNODE, m = rem % NNODE;
  Abuf[idx] = 2.f*Abuf[idx]/lam[b] - (n==m ? 1.f : 0.f);
}

// causal conv(3) + GLU -> t_feat (B,T,N,32)
__global__ __launch_bounds__(256) void k_tcn(const float* __restrict__ x,
    const float* __restrict__ w, const float* __restrict__ bcn, float* __restrict__ tfeat){
  int idx = blockIdx.x*256 + threadIdx.x;
  if (idx >= BTN*32) return;
  int o = idx & 31; int r = idx >> 5;
  int n = r % NNODE, bt = r / NNODE, t = bt % NT, b = bt / NT;
  float t0 = (t>=2)? x[((size_t)(b*NT+t-2)*NNODE+n)*NF] : 0.f;
  float t1 = (t>=1)? x[((size_t)(b*NT+t-1)*NNODE+n)*NF] : 0.f;
  float t2 = x[((size_t)(b*NT+t)*NNODE+n)*NF];
  float P = bcn[o]    + w[o*3]*t0       + w[o*3+1]*t1       + w[o*3+2]*t2;
  float Q = bcn[o+32] + w[(o+32)*3]*t0  + w[(o+32)*3+1]*t1  + w[(o+32)*3+2]*t2;
  tfeat[(size_t)r*32 + o] = P * sigf(Q);
}

// RB = tfeat@th1 -> P2 ; RC = tfeat@th2 -> P1     layout (B, N, T*32)
__global__ __launch_bounds__(256) void k_thetaBC(const float* __restrict__ tfeat,
    const float* __restrict__ theta, float* __restrict__ P2, float* __restrict__ P1){
  __shared__ float thB[32][33], thC[32][33];
  __shared__ float tf[8][32];
  int tid = threadIdx.x;
  for (int i=tid; i<1024; i+=256){
    int f = i >> 5, o = i & 31;
    thB[o][f] = theta[1024+f*32+o]; thC[o][f] = theta[2048+f*32+o];
  }
  int rl = tid >> 5, o = tid & 31;
  int r = blockIdx.x*8 + rl;
  tf[rl][o] = tfeat[(size_t)r*32 + o];
  __syncthreads();
  float aB=0.f, aC=0.f;
  #pragma unroll
  for (int f=0; f<32; ++f){
    float t = tf[rl][f];
    aB += t*thB[o][f]; aC += t*thC[o][f];
  }
  int n = r % NNODE, bt = r / NNODE, t = bt % NT, b = bt / NT;
  size_t outi = (size_t)(b*NNODE+n)*G3 + t*32 + o;
  P2[outi]=aB; P1[outi]=aC;
}

// RA = tfeat@(th0-th2) -> P1
__global__ __launch_bounds__(256) void k_thetaA(const float* __restrict__ tfeat,
    const float* __restrict__ theta, float* __restrict__ P1){
  __shared__ float thA[32][33];
  __shared__ float tf[8][32];
  int tid = threadIdx.x;
  for (int i=tid; i<1024; i+=256){
    int f = i >> 5, o = i & 31;
    thA[o][f] = theta[f*32+o] - theta[2048+f*32+o];
  }
  int rl = tid >> 5, o = tid & 31;
  int r = blockIdx.x*8 + rl;
  tf[rl][o] = tfeat[(size_t)r*32 + o];
  __syncthreads();
  float aA=0.f;
  #pragma unroll
  for (int f=0; f<32; ++f) aA += tf[rl][f]*thA[o][f];
  int n = r % NNODE, bt = r / NNODE, t = bt % NT, b = bt / NT;
  P1[(size_t)(b*NNODE+n)*G3 + t*32 + o] = aA;
}

// ---------- 128x128-tile GEMMs, 8x8 per thread ----------

// C = A(M,K) @ W(N,K)^T + bias ; arbitrary lda/ldw (scalar fallback if !16B)
__global__ __launch_bounds__(256) void gemm_nt128(const float* __restrict__ A, int lda,
    const float* __restrict__ W, int ldw, const float* __restrict__ bias,
    float* __restrict__ C, int M, int N, int K){
  __shared__ float As[16][132];
  __shared__ float Ws[16][132];
  int n0 = blockIdx.x*128, m0 = blockIdx.y*128;
  int tid = threadIdx.x, tx = tid & 15, ty = tid >> 4;
  float acc[8][8] = {};
  int lr = tid >> 1, lk = (tid & 1)*8;
  const bool a4 = ((lda & 3) == 0), w4 = ((ldw & 3) == 0);
  for (int k0=0; k0<K; k0+=16){
    {
      int m = m0 + lr;
      if (m < M){
        const float* ap = A + (size_t)m*lda + k0 + lk;
        if (a4 && (k0+lk+8) <= K){
          float4 v0 = *(const float4*)ap, v1 = *(const float4*)(ap+4);
          As[lk+0][lr]=v0.x; As[lk+1][lr]=v0.y; As[lk+2][lr]=v0.z; As[lk+3][lr]=v0.w;
          As[lk+4][lr]=v1.x; As[lk+5][lr]=v1.y; As[lk+6][lr]=v1.z; As[lk+7][lr]=v1.w;
        } else {
          #pragma unroll
          for (int j=0;j<8;++j){ int k=k0+lk+j; As[lk+j][lr] = (k<K) ? ap[j] : 0.f; }
        }
      } else {
        #pragma unroll
        for (int j=0;j<8;++j) As[lk+j][lr] = 0.f;
      }
      int nn = n0 + lr;
      if (nn < N){
        const float* wp = W + (size_t)nn*ldw + k0 + lk;
        if (w4 && (k0+lk+8) <= K){
          float4 v0 = *(const float4*)wp, v1 = *(const float4*)(wp+4);
          Ws[lk+0][lr]=v0.x; Ws[lk+1][lr]=v0.y; Ws[lk+2][lr]=v0.z; Ws[lk+3][lr]=v0.w;
          Ws[lk+4][lr]=v1.x; Ws[lk+5][lr]=v1.y; Ws[lk+6][lr]=v1.z; Ws[lk+7][lr]=v1.w;
        } else {
          #pragma unroll
          for (int j=0;j<8;++j){ int k=k0+lk+j; Ws[lk+j][lr] = (k<K) ? wp[j] : 0.f; }
        }
      } else {
        #pragma unroll
        for (int j=0;j<8;++j) Ws[lk+j][lr] = 0.f;
      }
    }
    __syncthreads();
    #pragma unroll
    for (int kk=0;kk<16;++kk){
      float4 a0 = *(const float4*)&As[kk][ty*8];
      float4 a1 = *(const float4*)&As[kk][ty*8+4];
      float4 b0 = *(const float4*)&Ws[kk][tx*4];
      float4 b1 = *(const float4*)&Ws[kk][64+tx*4];
      float av[8] = {a0.x,a0.y,a0.z,a0.w,a1.x,a1.y,a1.z,a1.w};
      float bv[8] = {b0.x,b0.y,b0.z,b0.w,b1.x,b1.y,b1.z,b1.w};
      #pragma unroll
      for (int i=0;i<8;++i)
        #pragma unroll
        for (int j=0;j<8;++j) acc[i][j] += av[i]*bv[j];
    }
    __syncthreads();
  }
  float bl[4], bh[4];
  #pragma unroll
  for (int j=0;j<4;++j){ bl[j] = bias[n0+tx*4+j]; bh[j] = bias[n0+64+tx*4+j]; }
  #pragma unroll
  for (int i=0;i<8;++i){
    int m = m0 + ty*8 + i; if (m >= M) continue;
    float4 s0, s1;
    s0.x = acc[i][0]+bl[0]; s0.y = acc[i][1]+bl[1]; s0.z = acc[i][2]+bl[2]; s0.w = acc[i][3]+bl[3];
    s1.x = acc[i][4]+bh[0]; s1.y = acc[i][5]+bh[1]; s1.z = acc[i][6]+bh[2]; s1.w = acc[i][7]+bh[3];
    *(float4*)&C[(size_t)m*N + n0 + tx*4] = s0;
    *(float4*)&C[(size_t)m*N + n0 + 64 + tx*4] = s1;
  }
}

// batched C[b] = alpha*(A[b](M,K) @ X[b](K,N)) + beta*Y[b] (opt relu); A scalar-staged
__global__ __launch_bounds__(256) void gemm_nn128(const float* __restrict__ Ab,
    const float* __restrict__ Xb, const float* __restrict__ Yb, float* __restrict__ Cb,
    int M, int N, int K, int sA, int sX, int sY, int sC,
    float alphaV, float betaV, int do_relu){
  __shared__ float As[16][132];
  __shared__ float Xs[16][132];
  int b = blockIdx.z;
  const float* A = Ab + (size_t)b*sA;
  const float* X = Xb + (size_t)b*sX;
  const float* Y = Yb + (size_t)b*sY;
  float* C = Cb + (size_t)b*sC;
  int n0 = blockIdx.x*128, m0 = blockIdx.y*128;
  int tid = threadIdx.x, tx = tid & 15, ty = tid >> 4;
  float acc[8][8] = {};
  int lr = tid >> 1, lk = (tid & 1)*8;
  int xk = tid >> 4, xc = (tid & 15)*4;
  for (int k0=0; k0<K; k0+=16){
    {
      int m = m0 + lr;
      if (m < M){
        const float* ap = A + (size_t)m*K + k0 + lk;
        #pragma unroll
        for (int j=0;j<8;++j){ int k=k0+lk+j; As[lk+j][lr] = (k<K) ? ap[j] : 0.f; }
      } else {
        #pragma unroll
        for (int j=0;j<8;++j) As[lk+j][lr] = 0.f;
      }
      int k = k0 + xk;
      if (k < K){
        const float* xp = X + (size_t)k*N + n0;
        *(float4*)&Xs[xk][xc]    = *(const float4*)(xp + xc);
        *(float4*)&Xs[xk][64+xc] = *(const float4*)(xp + 64 + xc);
      } else {
        *(float4*)&Xs[xk][xc]    = make_float4(0.f,0.f,0.f,0.f);
        *(float4*)&Xs[xk][64+xc] = make_float4(0.f,0.f,0.f,0.f);
      }
    }
    __syncthreads();
    #pragma unroll
    for (int kk=0;kk<16;++kk){
      float4 a0 = *(const float4*)&As[kk][ty*8];
      float4 a1 = *(const float4*)&As[kk][ty*8+4];
      float4 b0 = *(const float4*)&Xs[kk][tx*4];
      float4 b1 = *(const float4*)&Xs[kk][64+tx*4];
      float av[8] = {a0.x,a0.y,a0.z,a0.w,a1.x,a1.y,a1.z,a1.w};
      float bv[8] = {b0.x,b0.y,b0.z,b0.w,b1.x,b1.y,b1.z,b1.w};
      #pragma unroll
      for (int i=0;i<8;++i)
        #pragma unroll
        for (int j=0;j<8;++j) acc[i][j] += av[i]*bv[j];
    }
    __syncthreads();
  }
  #pragma unroll
  for (int i=0;i<8;++i){
    int m = m0 + ty*8 + i; if (m >= M) continue;
    const float* yr = Y + (size_t)m*N;
    float* cr = C + (size_t)m*N;
    float4 y0 = *(const float4*)(yr + n0 + tx*4);
    float4 y1 = *(const float4*)(yr + n0 + 64 + tx*4);
    float4 s0, s1;
    s0.x = alphaV*acc[i][0] + betaV*y0.x; s0.y = alphaV*acc[i][1] + betaV*y0.y;
    s0.z = alphaV*acc[i][2] + betaV*y0.z; s0.w = alphaV*acc[i][3] + betaV*y0.w;
    s1.x = alphaV*acc[i][4] + betaV*y1.x; s1.y = alphaV*acc[i][5] + betaV*y1.y;
    s1.z = alphaV*acc[i][6] + betaV*y1.z; s1.w = alphaV*acc[i][7] + betaV*y1.w;
    if (do_relu){
      s0.x = fmaxf(s0.x,0.f); s0.y = fmaxf(s0.y,0.f); s0.z = fmaxf(s0.z,0.f); s0.w = fmaxf(s0.w,0.f);
      s1.x = fmaxf(s1.x,0.f); s1.y = fmaxf(s1.y,0.f); s1.z = fmaxf(s1.z,0.f); s1.w = fmaxf(s1.w,0.f);
    }
    *(float4*)(cr + n0 + tx*4) = s0;
    *(float4*)(cr + n0 + 64 + tx*4) = s1;
  }
}

// fusion, attn gate, write z in (tau, i, 65) layout + ctx + pred0
__global__ __launch_bounds__(256) void k_zbuild(const float* __restrict__ x,
    const float* __restrict__ S, const float* __restrict__ cw, const float* __restrict__ cb,
    const float* __restrict__ aw, const float* __restrict__ ab,
    float* __restrict__ ztm, float* __restrict__ ctx, float* __restrict__ pred0){
  int tid = threadIdx.x;
  int rl = tid >> 6, l = tid & 63;
  int r = blockIdx.x*4 + rl;
  int n = r % NNODE, bt = r / NNODE, t = bt % NT, b = bt / NT;
  const float* xr = x + (size_t)r*NF;
  float fu, fu64 = 0.f;
  if (l == 0){
    fu = xr[0];
    float s_ = cb[31];
    #pragma unroll
    for (int f=0; f<13; ++f) s_ += xr[1+f]*cw[31*13+f];
    fu64 = s_ > 0.f ? s_ : 0.f;
  } else if (l < 33){
    fu = S[(size_t)(b*NNODE+n)*G3 + t*32 + (l-1)];
  } else {
    int o = l - 33;
    float s_ = cb[o];
    #pragma unroll
    for (int f=0; f<13; ++f) s_ += xr[1+f]*cw[o*13+f];
    fu = s_ > 0.f ? s_ : 0.f;
  }
  float part = fu*aw[l] + (l==0 ? fu64*aw[64] : 0.f);
  #pragma unroll
  for (int off=32; off; off>>=1) part += __shfl_down(part, off, 64);
  part = __shfl(part, 0, 64);
  float attn = sigf(part + ab[0]);
  int i_ = r / NT, tau = r % NT;          // scrambled reshape (B*N, T, 65)
  float* zr = ztm + ((size_t)tau*ROWS + i_)*65;
  zr[l] = fu*attn;
  if (l == 0) zr[64] = fu64*attn;
  if (t == NT-1){
    if (l >= 33) ctx[(size_t)(b*NNODE+n)*32 + (l-33)] = fu;
    if (l == 0){ ctx[(size_t)(b*NNODE+n)*32 + 31] = fu64; pred0[b*NNODE+n] = xr[0]; }
  }
}

__global__ __launch_bounds__(256) void k_gru(const float* __restrict__ gX,
    const float* __restrict__ gH, float* __restrict__ h){
  int idx = blockIdx.x*256 + threadIdx.x;
  if (idx >= ROWS*NH/4) return;
  int i = idx >> 5, jj = (idx & 31)*4;
  const float* gx = gX + (size_t)i*G3 + jj;
  const float* gh = gH + (size_t)i*G3 + jj;
  float4 gx0 = *(const float4*)gx, gx1 = *(const float4*)(gx+NH), gx2 = *(const float4*)(gx+2*NH);
  float4 gh0 = *(const float4*)gh, gh1 = *(const float4*)(gh+NH), gh2 = *(const float4*)(gh+2*NH);
  float4 hv = *(float4*)(h + (size_t)i*NH + jj);
  float r, z, nn;
  r = sigf(gx0.x+gh0.x); z = sigf(gx1.x+gh1.x); nn = tanhf(gx2.x + r*gh2.x); hv.x = (1.f-z)*nn + z*hv.x;
  r = sigf(gx0.y+gh0.y); z = sigf(gx1.y+gh1.y); nn = tanhf(gx2.y + r*gh2.y); hv.y = (1.f-z)*nn + z*hv.y;
  r = sigf(gx0.z+gh0.z); z = sigf(gx1.z+gh1.z); nn = tanhf(gx2.z + r*gh2.z); hv.z = (1.f-z)*nn + z*hv.z;
  r = sigf(gx0.w+gh0.w); z = sigf(gx1.w+gh1.w); nn = tanhf(gx2.w + r*gh2.w); hv.w = (1.f-z)*nn + z*hv.w;
  *(float4*)(h + (size_t)i*NH + jj) = hv;
}

__global__ __launch_bounds__(128) void k_dec(const float* __restrict__ ctxGX,
    const float* __restrict__ gH, const float* __restrict__ wih,
    const float* __restrict__ ow, const float* __restrict__ ob,
    float* __restrict__ h, float* __restrict__ pred, float* __restrict__ preds_out){
  __shared__ float ssum[2];
  int i = blockIdx.x, j = threadIdx.x;
  float p = pred[i];
  const float* gx = ctxGX + (size_t)i*G3;
  const float* gh = gH + (size_t)i*G3;
  float r  = sigf(gx[j]      + p*wih[j*33]        + gh[j]);
  float z  = sigf(gx[NH+j]   + p*wih[(NH+j)*33]   + gh[NH+j]);
  float nn = tanhf(gx[2*NH+j] + p*wih[(2*NH+j)*33] + r*gh[2*NH+j]);
  float h2 = (1.f - z)*nn + z*h[(size_t)i*NH + j];
  h[(size_t)i*NH + j] = h2;
  float part = h2*ow[j];
  #pragma unroll
  for (int off=32; off; off>>=1) part += __shfl_down(part, off, 64);
  if ((j & 63) == 0) ssum[j >> 6] = part;
  __syncthreads();
  if (j == 0){
    float pn = ssum[0] + ssum[1] + ob[0];
    pred[i] = pn; preds_out[i] = pn;
  }
}

__global__ __launch_bounds__(256) void k_out(const float* __restrict__ preds, float* __restrict__ out){
  int idx = blockIdx.x*256 + threadIdx.x;
  if (idx >= NT*ROWS) return;
  int n = idx % NNODE;
  int t2 = idx / NNODE;
  int hor = t2 % NT;
  int b = t2 / NT;
  out[idx] = preds[(size_t)hor*ROWS + b*NNODE + n];
}

extern "C" void kernel_launch(void* const* d_in, const int* in_sizes, int n_in,
                              void* d_out, int out_size, void* d_ws, size_t ws_size,
                              hipStream_t stream){
  const float* x     = (const float*)d_in[0];
  const float* Aph   = (const float*)d_in[1];
  const float* fcw   = (const float*)d_in[2];
  const float* fcb   = (const float*)d_in[3];
  const float* alp   = (const float*)d_in[4];
  const float* cw    = (const float*)d_in[5];
  const float* cb    = (const float*)d_in[6];
  const float* tw    = (const float*)d_in[7];
  const float* tb    = (const float*)d_in[8];
  const float* theta = (const float*)d_in[9];
  const float* aw    = (const float*)d_in[10];
  const float* ab    = (const float*)d_in[11];
  const float* ewih  = (const float*)d_in[12];
  const float* ewhh  = (const float*)d_in[13];
  const float* ebih  = (const float*)d_in[14];
  const float* ebhh  = (const float*)d_in[15];
  const float* dwih  = (const float*)d_in[16];
  const float* dwhh  = (const float*)d_in[17];
  const float* dbih  = (const float*)d_in[18];
  const float* dbhh  = (const float*)d_in[19];
  const float* ow    = (const float*)d_in[20];
  const float* ob    = (const float*)d_in[21];
  float* out = (float*)d_out;

  const size_t SZ_H    = (size_t)ROWS*NH;
  const size_t SZ_CTX  = (size_t)ROWS*32;
  const size_t SZ_PRED = (size_t)ROWS;
  const size_t SZ_PREDS= (size_t)NT*ROWS;
  const size_t SZ_G    = (size_t)ROWS*G3;
  const size_t SZ_ABUF = (size_t)NB*NNODE*NNODE;
  const size_t SZ_EMB  = (size_t)ROWS*16;
  const size_t SZ_Z    = (size_t)NT*ROWS*65;

  float* w = (float*)d_ws;
  size_t off = 0;
  auto alloc = [&](size_t nfl){ float* p = w + off; off += nfl; return p; };
  float* h     = alloc(SZ_H);
  float* ctx   = alloc(SZ_CTX);
  float* pred  = alloc(SZ_PRED);
  float* preds = alloc(SZ_PREDS);
  float* gH    = alloc(SZ_G);
  float* Abuf  = alloc(SZ_ABUF);
  float* emb   = alloc(SZ_EMB);
  float* rsum  = alloc(SZ_PRED);
  float* lam   = alloc((size_t)NB);
  float* Sslot = alloc(SZ_G);      // t_feat -> S -> gX -> ctxGX
  float* Zzone = alloc(SZ_Z > 2*SZ_G ? SZ_Z : 2*SZ_G);  // P1|P2 ; later z (tau,i,65)
  float* P1 = Zzone;
  float* P2 = Zzone + SZ_G;
  (void)n_in; (void)in_sizes;

  if (ws_size < off*sizeof(float)){    // tripwire: workspace too small
    k_sentinel<<<(out_size+255)/256, 256, 0, stream>>>(out, out_size);
    return;
  }

  float* tfeat = Sslot;
  k_emb<<<(ROWS*16)/256, 256, 0, stream>>>(x, fcw, fcb, emb);
  k_adj<<<ROWS/4, 256, 0, stream>>>(emb, Aph, alp, Abuf, rsum);
  k_lam<<<NB, 256, 0, stream>>>(rsum, lam);
  k_lap<<<(NB*NNODE*NNODE + 255)/256, 256, 0, stream>>>(Abuf, lam);
  k_tcn<<<(BTN*32)/256, 256, 0, stream>>>(x, tw, tb, tfeat);
  k_thetaBC<<<BTN/8, 256, 0, stream>>>(tfeat, theta, P2, P1);
  // P2 <- 2*(L @ P1) + P2
  gemm_nn128<<<dim3(3, 2, NB), 256, 0, stream>>>(Abuf, P1, P2, P2,
      NNODE, G3, NNODE, NNODE*NNODE, NNODE*G3, NNODE*G3, NNODE*G3, 2.f, 1.f, 0);
  k_thetaA<<<BTN/8, 256, 0, stream>>>(tfeat, theta, P1);
  // Sslot <- relu((L @ P2) + P1)
  gemm_nn128<<<dim3(3, 2, NB), 256, 0, stream>>>(Abuf, P2, P1, Sslot,
      NNODE, G3, NNODE, NNODE*NNODE, NNODE*G3, NNODE*G3, NNODE*G3, 1.f, 1.f, 1);
  k_zbuild<<<BTN/4, 256, 0, stream>>>(x, Sslot, cw, cb, aw, ab, Zzone, ctx, pred);
  hipMemsetAsync(h, 0, SZ_H*sizeof(float), stream);

  float* gX = Sslot;   // S dead after zbuild
  for (int t=0; t<NT; ++t){
    gemm_nt128<<<dim3(3, 207), 256, 0, stream>>>(Zzone + (size_t)t*ROWS*65, 65,
        ewih, 65, ebih, gX, ROWS, G3, 65);
    gemm_nt128<<<dim3(3, 207), 256, 0, stream>>>(h, NH, ewhh, NH, ebhh, gH,
        ROWS, G3, NH);
    k_gru<<<(ROWS*NH/4 + 255)/256, 256, 0, stream>>>(gX, gH, h);
  }
  float* ctxGX = Sslot;  // gX dead after encoder
  gemm_nt128<<<dim3(3, 207), 256, 0, stream>>>(ctx, 32, dwih+1, 33, dbih,
      ctxGX, ROWS, G3, 32);
  for (int s=0; s<NT; ++s){
    gemm_nt128<<<dim3(3, 207), 256, 0, stream>>>(h, NH, dwhh, NH, dbhh, gH,
        ROWS, G3, NH);
    k_dec<<<ROWS, 128, 0, stream>>>(ctxGX, gH, dwih, ow, ob, h, pred,
        preds + (size_t)s*ROWS);
  }
  k_out<<<(NT*ROWS)/256, 256, 0, stream>>>(preds, out);
}

// Round 4
// 2008.495 us; speedup vs baseline: 2.2516x; 1.3387x over previous
//
#include <hip/hip_runtime.h>
#include <math.h>

#define NB 128      // B
#define NT 12       // T
#define NNODE 207   // N
#define NF 14       // F
#define NH 128      // H
#define ROWS (NB*NNODE)      // 26496
#define BTN (NB*NT*NNODE)    // 317952
#define G3 (3*NH)            // 384
#define LSTR 208             // padded Laplacian row stride
#define ZSTR 80              // padded z row stride (65 -> 80, 5 chunks of 16)

__device__ __forceinline__ float sigf(float x){ return 1.0f/(1.0f+__expf(-x)); }

__global__ __launch_bounds__(256) void k_sentinel(float* __restrict__ out, int n){
  int i = blockIdx.x*256 + threadIdx.x;
  if (i < n) out[i] = 12345.0f;
}

// transpose weights into K x 384 layouts (+ zero-pad), extract dwih col 0
#define OFF_EWIHT 0
#define OFF_EWHHT (80*384)
#define OFF_DWHHT (80*384 + 128*384)
#define OFF_DWIHT (80*384 + 2*128*384)
#define OFF_W0    (80*384 + 2*128*384 + 32*384)
#define WT_TOTAL  (80*384 + 2*128*384 + 32*384 + 384)
__global__ __launch_bounds__(256) void k_prep(const float* __restrict__ ewih,
    const float* __restrict__ ewhh, const float* __restrict__ dwih,
    const float* __restrict__ dwhh, float* __restrict__ wt){
  int i = blockIdx.x*256 + threadIdx.x;
  if (i < OFF_EWHHT){
    int k = i/384, n = i%384;
    wt[i] = (k < 65) ? ewih[n*65 + k] : 0.f;
  } else if (i < OFF_DWHHT){
    int j = i - OFF_EWHHT; int k = j/384, n = j%384;
    wt[i] = ewhh[n*128 + k];
  } else if (i < OFF_DWIHT){
    int j = i - OFF_DWHHT; int k = j/384, n = j%384;
    wt[i] = dwhh[n*128 + k];
  } else if (i < OFF_W0){
    int j = i - OFF_DWIHT; int k = j/384, n = j%384;
    wt[i] = dwih[n*33 + 1 + k];
  } else if (i < WT_TOTAL){
    int n = i - OFF_W0;
    wt[i] = dwih[n*33];
  }
}

// emb = tanh(state * fc_w + fc_b)   (B,N,16)
__global__ __launch_bounds__(256) void k_emb(const float* __restrict__ x,
    const float* __restrict__ w, const float* __restrict__ b, float* __restrict__ emb){
  int idx = blockIdx.x*256 + threadIdx.x;
  if (idx >= ROWS*16) return;
  int j = idx & 15, row = idx >> 4;
  int bb = row / NNODE, n = row % NNODE;
  float s = x[((bb*NT + (NT-1))*NNODE + n)*NF];
  emb[idx] = tanhf(s*w[j] + b[j]);
}

// wave-per-row: A_dyn row, top-10 (tie->lowest idx), sparse softmax, blend, rowsum
__global__ __launch_bounds__(256) void k_adj(const float* __restrict__ emb,
    const float* __restrict__ Aph, const float* __restrict__ alp,
    float* __restrict__ Abuf, float* __restrict__ rsum){
  int wid = threadIdx.x >> 6, lane = threadIdx.x & 63;
  int row = blockIdx.x*4 + wid;
  int bb = row / NNODE, n = row % NNODE;
  const float4* er = (const float4*)(emb + (size_t)row*16);
  float4 e0 = er[0], e1 = er[1], e2 = er[2], e3 = er[3];
  float d[4];
  #pragma unroll
  for (int q=0;q<4;++q){
    int m = lane + q*64;
    float dd = -1.f;
    if (m < NNODE){
      const float4* em = (const float4*)(emb + (size_t)(bb*NNODE+m)*16);
      float4 m0 = em[0], m1 = em[1], m2 = em[2], m3 = em[3];
      dd = e0.x*m0.x + e0.y*m0.y + e0.z*m0.z + e0.w*m0.w
         + e1.x*m1.x + e1.y*m1.y + e1.z*m1.z + e1.w*m1.w
         + e2.x*m2.x + e2.y*m2.y + e2.z*m2.z + e2.w*m2.w
         + e3.x*m3.x + e3.y*m3.y + e3.z*m3.z + e3.w*m3.w;
      dd = dd > 0.f ? dd : 0.f;
    }
    d[q] = dd;
  }
  int km = 0;
  float vmax = 0.f;
  for (int it=0; it<10; ++it){
    float v = -1.f; int mi = 1<<20;
    #pragma unroll
    for (int q=0;q<4;++q){
      if (d[q] >= 0.f && !((km>>q)&1) && d[q] > v){ v = d[q]; mi = lane + q*64; }
    }
    #pragma unroll
    for (int off=1; off<64; off<<=1){
      float v2 = __shfl_xor(v, off, 64);
      int  i2 = __shfl_xor(mi, off, 64);
      if (v2 > v || (v2 == v && i2 < mi)){ v = v2; mi = i2; }
    }
    if (it == 0) vmax = v;
    if ((mi & 63) == lane) km |= 1 << (mi >> 6);
  }
  float a = sigf(alp[0]);
  float eneg = __expf(-vmax);
  float p[4]; float ps = 0.f;
  #pragma unroll
  for (int q=0;q<4;++q){
    p[q] = 0.f;
    if (d[q] >= 0.f) p[q] = ((km>>q)&1) ? __expf(d[q]-vmax) : eneg;
    ps += p[q];
  }
  #pragma unroll
  for (int off=1; off<64; off<<=1) ps += __shfl_xor(ps, off, 64);
  float inv = (1.f - a)/ps;
  float rs = 0.f;
  #pragma unroll
  for (int q=0;q<4;++q){
    int m = lane + q*64;
    if (m < NNODE){
      float Av = a*Aph[n*NNODE + m] + p[q]*inv;
      Abuf[(size_t)row*LSTR + m] = Av;
      rs += Av;
    }
  }
  if (lane == 0) Abuf[(size_t)row*LSTR + 207] = 0.f;   // pad col
  #pragma unroll
  for (int off=1; off<64; off<<=1) rs += __shfl_xor(rs, off, 64);
  if (lane == 0) rsum[row] = rs;
}

__global__ __launch_bounds__(256) void k_lam(const float* __restrict__ rsum, float* __restrict__ lam){
  __shared__ float rv[256];
  int b = blockIdx.x, tid = threadIdx.x;
  rv[tid] = (tid < NNODE) ? rsum[b*NNODE+tid] : -1e30f;
  __syncthreads();
  for (int s=128;s>0;s>>=1){ if (tid<s) rv[tid]=fmaxf(rv[tid],rv[tid+s]); __syncthreads(); }
  if (tid==0) lam[b] = fmaxf(rv[0], 1.0f);
}

__global__ __launch_bounds__(256) void k_lap(float* __restrict__ Abuf, const float* __restrict__ lam){
  int idx = blockIdx.x*256 + threadIdx.x;
  if (idx >= NB*NNODE*LSTR) return;
  int b = idx / (NNODE*LSTR);
  int rem = idx % (NNODE*LSTR);
  int n = rem / LSTR, m = rem % LSTR;
  Abuf[idx] = 2.f*Abuf[idx]/lam[b] - (n==m ? 1.f : 0.f);   // m==207: 0 stays 0
}

// causal conv(3) + GLU -> t_feat (B,T,N,32)
__global__ __launch_bounds__(256) void k_tcn(const float* __restrict__ x,
    const float* __restrict__ w, const float* __restrict__ bcn, float* __restrict__ tfeat){
  int idx = blockIdx.x*256 + threadIdx.x;
  if (idx >= BTN*32) return;
  int o = idx & 31; int r = idx >> 5;
  int n = r % NNODE, bt = r / NNODE, t = bt % NT, b = bt / NT;
  float t0 = (t>=2)? x[((size_t)(b*NT+t-2)*NNODE+n)*NF] : 0.f;
  float t1 = (t>=1)? x[((size_t)(b*NT+t-1)*NNODE+n)*NF] : 0.f;
  float t2 = x[((size_t)(b*NT+t)*NNODE+n)*NF];
  float P = bcn[o]    + w[o*3]*t0       + w[o*3+1]*t1       + w[o*3+2]*t2;
  float Q = bcn[o+32] + w[(o+32)*3]*t0  + w[(o+32)*3+1]*t1  + w[(o+32)*3+2]*t2;
  tfeat[(size_t)r*32 + o] = P * sigf(Q);
}

// RB = tfeat@th1 -> P2 ; RC = tfeat@th2 -> P1     layout (B, N, T*32)
__global__ __launch_bounds__(256) void k_thetaBC(const float* __restrict__ tfeat,
    const float* __restrict__ theta, float* __restrict__ P2, float* __restrict__ P1){
  __shared__ float thB[32][33], thC[32][33];
  __shared__ float tf[8][32];
  int tid = threadIdx.x;
  for (int i=tid; i<1024; i+=256){
    int f = i >> 5, o = i & 31;
    thB[o][f] = theta[1024+f*32+o]; thC[o][f] = theta[2048+f*32+o];
  }
  int rl = tid >> 5, o = tid & 31;
  int r = blockIdx.x*8 + rl;
  tf[rl][o] = tfeat[(size_t)r*32 + o];
  __syncthreads();
  float aB=0.f, aC=0.f;
  #pragma unroll
  for (int f=0; f<32; ++f){
    float t = tf[rl][f];
    aB += t*thB[o][f]; aC += t*thC[o][f];
  }
  int n = r % NNODE, bt = r / NNODE, t = bt % NT, b = bt / NT;
  size_t outi = (size_t)(b*NNODE+n)*G3 + t*32 + o;
  P2[outi]=aB; P1[outi]=aC;
}

// RA = tfeat@(th0-th2) -> P1
__global__ __launch_bounds__(256) void k_thetaA(const float* __restrict__ tfeat,
    const float* __restrict__ theta, float* __restrict__ P1){
  __shared__ float thA[32][33];
  __shared__ float tf[8][32];
  int tid = threadIdx.x;
  for (int i=tid; i<1024; i+=256){
    int f = i >> 5, o = i & 31;
    thA[o][f] = theta[f*32+o] - theta[2048+f*32+o];
  }
  int rl = tid >> 5, o = tid & 31;
  int r = blockIdx.x*8 + rl;
  tf[rl][o] = tfeat[(size_t)r*32 + o];
  __syncthreads();
  float aA=0.f;
  #pragma unroll
  for (int f=0; f<32; ++f) aA += tf[rl][f]*thA[o][f];
  int n = r % NNODE, bt = r / NNODE, t = bt % NT, b = bt / NT;
  P1[(size_t)(b*NNODE+n)*G3 + t*32 + o] = aA;
}

// ---- unified 128x128 GEMM: C = [alpha*](A @ B) + bias|beta*Y [relu]
// A: (M, K) row-major lda (lda%4==0, K padded to 16*kchunks with harmless cols)
// B: (16*kchunks, 384) row-major (padded rows must be zero OR A pad cols zero)
// N hard-coded 384; grid (3, ceil(M/128), nbatch)
__global__ __launch_bounds__(256) void gemm128(
    const float* __restrict__ Ab, int lda, long long sA,
    const float* __restrict__ Bb, long long sB,
    const float* __restrict__ bias,
    const float* __restrict__ Yb, long long sY, float alphaV, float betaV, int do_relu,
    float* __restrict__ Cb, long long sC, int M, int kchunks){
  __shared__ float As[16][132];
  __shared__ float Bs[16][132];
  int bz = blockIdx.z;
  const float* A = Ab + (size_t)bz*sA;
  const float* B = Bb + (size_t)bz*sB;
  float* C = Cb + (size_t)bz*sC;
  int n0 = blockIdx.x*128, m0 = blockIdx.y*128;
  int tid = threadIdx.x, tx = tid & 15, ty = tid >> 4;
  float acc[8][8] = {};
  int ar = tid & 127, ak = (tid >> 7)*8;
  int bk = tid >> 4, bn = (tid & 15)*8;
  for (int kc=0; kc<kchunks; ++kc){
    int k0 = kc*16;
    int m = m0 + ar;
    if (m < M){
      const float* ap = A + (size_t)m*lda + k0 + ak;
      float4 v0 = *(const float4*)ap, v1 = *(const float4*)(ap+4);
      As[ak+0][ar]=v0.x; As[ak+1][ar]=v0.y; As[ak+2][ar]=v0.z; As[ak+3][ar]=v0.w;
      As[ak+4][ar]=v1.x; As[ak+5][ar]=v1.y; As[ak+6][ar]=v1.z; As[ak+7][ar]=v1.w;
    } else {
      #pragma unroll
      for (int j=0;j<8;++j) As[ak+j][ar]=0.f;
    }
    const float* bp = B + (size_t)(k0+bk)*384 + n0 + bn;
    float4 w0_ = *(const float4*)bp, w1_ = *(const float4*)(bp+4);
    *(float4*)&Bs[bk][bn] = w0_; *(float4*)&Bs[bk][bn+4] = w1_;
    __syncthreads();
    #pragma unroll
    for (int kk=0;kk<16;++kk){
      float4 a0 = *(const float4*)&As[kk][ty*8];
      float4 a1 = *(const float4*)&As[kk][ty*8+4];
      float4 b0 = *(const float4*)&Bs[kk][tx*4];
      float4 b1 = *(const float4*)&Bs[kk][64+tx*4];
      float av[8] = {a0.x,a0.y,a0.z,a0.w,a1.x,a1.y,a1.z,a1.w};
      float bv[8] = {b0.x,b0.y,b0.z,b0.w,b1.x,b1.y,b1.z,b1.w};
      #pragma unroll
      for (int i=0;i<8;++i)
        #pragma unroll
        for (int j=0;j<8;++j) acc[i][j] += av[i]*bv[j];
    }
    __syncthreads();
  }
  if (bias){
    float bl[4], bh_[4];
    #pragma unroll
    for (int j=0;j<4;++j){ bl[j]=bias[n0+tx*4+j]; bh_[j]=bias[n0+64+tx*4+j]; }
    #pragma unroll
    for (int i=0;i<8;++i){
      int m2 = m0 + ty*8 + i; if (m2 >= M) continue;
      float4 s0, s1;
      s0.x=acc[i][0]+bl[0]; s0.y=acc[i][1]+bl[1]; s0.z=acc[i][2]+bl[2]; s0.w=acc[i][3]+bl[3];
      s1.x=acc[i][4]+bh_[0]; s1.y=acc[i][5]+bh_[1]; s1.z=acc[i][6]+bh_[2]; s1.w=acc[i][7]+bh_[3];
      *(float4*)&C[(size_t)m2*384 + n0 + tx*4] = s0;
      *(float4*)&C[(size_t)m2*384 + n0 + 64 + tx*4] = s1;
    }
  } else {
    const float* Y = Yb + (size_t)bz*sY;
    #pragma unroll
    for (int i=0;i<8;++i){
      int m2 = m0 + ty*8 + i; if (m2 >= M) continue;
      const float* yr = Y + (size_t)m2*384;
      float* cr = C + (size_t)m2*384;
      float4 y0 = *(const float4*)(yr + n0 + tx*4);
      float4 y1 = *(const float4*)(yr + n0 + 64 + tx*4);
      float4 s0, s1;
      s0.x = alphaV*acc[i][0] + betaV*y0.x; s0.y = alphaV*acc[i][1] + betaV*y0.y;
      s0.z = alphaV*acc[i][2] + betaV*y0.z; s0.w = alphaV*acc[i][3] + betaV*y0.w;
      s1.x = alphaV*acc[i][4] + betaV*y1.x; s1.y = alphaV*acc[i][5] + betaV*y1.y;
      s1.z = alphaV*acc[i][6] + betaV*y1.z; s1.w = alphaV*acc[i][7] + betaV*y1.w;
      if (do_relu){
        s0.x=fmaxf(s0.x,0.f); s0.y=fmaxf(s0.y,0.f); s0.z=fmaxf(s0.z,0.f); s0.w=fmaxf(s0.w,0.f);
        s1.x=fmaxf(s1.x,0.f); s1.y=fmaxf(s1.y,0.f); s1.z=fmaxf(s1.z,0.f); s1.w=fmaxf(s1.w,0.f);
      }
      *(float4*)(cr + n0 + tx*4) = s0;
      *(float4*)(cr + n0 + 64 + tx*4) = s1;
    }
  }
}

// ---- fused encoder step: h' = GRU(gX_t, h @ ewhhT + bhh, h)
// 64 rows x 384 cols per block, 512 threads, acc 4x12
__global__ __launch_bounds__(512) void k_enc_fused(float* __restrict__ h,
    const float* __restrict__ BT, const float* __restrict__ bhh,
    const float* __restrict__ gX){
  __shared__ float As[16][68];
  __shared__ float Bs[16][388];
  int m0 = blockIdx.x*64;
  int tid = threadIdx.x, tx = tid & 31, ty = tid >> 5;
  float acc[4][12] = {};
  for (int k0=0; k0<NH; k0+=16){
    if (tid < 256){
      int r = tid & 63, kq = (tid >> 6)*4;
      float4 v = *(const float4*)&h[(size_t)(m0+r)*NH + k0 + kq];
      As[kq+0][r]=v.x; As[kq+1][r]=v.y; As[kq+2][r]=v.z; As[kq+3][r]=v.w;
    }
    {
      int kr = tid >> 5, cb = (tid & 31)*4;
      const float* bp = &BT[(size_t)(k0+kr)*384 + cb];
      *(float4*)&Bs[kr][cb]     = *(const float4*)(bp);
      *(float4*)&Bs[kr][cb+128] = *(const float4*)(bp+128);
      *(float4*)&Bs[kr][cb+256] = *(const float4*)(bp+256);
    }
    __syncthreads();
    #pragma unroll
    for (int kk=0;kk<16;++kk){
      float4 a = *(const float4*)&As[kk][ty*4];
      float4 b0 = *(const float4*)&Bs[kk][tx*4];
      float4 b1 = *(const float4*)&Bs[kk][tx*4+128];
      float4 b2 = *(const float4*)&Bs[kk][tx*4+256];
      float av[4] = {a.x,a.y,a.z,a.w};
      float bv[12] = {b0.x,b0.y,b0.z,b0.w,b1.x,b1.y,b1.z,b1.w,b2.x,b2.y,b2.z,b2.w};
      #pragma unroll
      for (int i=0;i<4;++i)
        #pragma unroll
        for (int j=0;j<12;++j) acc[i][j] += av[i]*bv[j];
    }
    __syncthreads();
  }
  int jc = tx*4;
  float4 bb0 = *(const float4*)&bhh[jc];
  float4 bb1 = *(const float4*)&bhh[jc+128];
  float4 bb2 = *(const float4*)&bhh[jc+256];
  #pragma unroll
  for (int rr=0;rr<4;++rr){
    int row = m0 + ty*4 + rr;
    const float* gx = gX + (size_t)row*384 + jc;
    float4 g0 = *(const float4*)gx;
    float4 g1 = *(const float4*)(gx+128);
    float4 g2 = *(const float4*)(gx+256);
    float4 hv = *(float4*)&h[(size_t)row*NH + jc];
    float r_, z_, n_;
    r_ = sigf(g0.x + acc[rr][0] + bb0.x); z_ = sigf(g1.x + acc[rr][4] + bb1.x);
    n_ = tanhf(g2.x + r_*(acc[rr][8] + bb2.x));  hv.x = (1.f-z_)*n_ + z_*hv.x;
    r_ = sigf(g0.y + acc[rr][1] + bb0.y); z_ = sigf(g1.y + acc[rr][5] + bb1.y);
    n_ = tanhf(g2.y + r_*(acc[rr][9] + bb2.y));  hv.y = (1.f-z_)*n_ + z_*hv.y;
    r_ = sigf(g0.z + acc[rr][2] + bb0.z); z_ = sigf(g1.z + acc[rr][6] + bb1.z);
    n_ = tanhf(g2.z + r_*(acc[rr][10] + bb2.z)); hv.z = (1.f-z_)*n_ + z_*hv.z;
    r_ = sigf(g0.w + acc[rr][3] + bb0.w); z_ = sigf(g1.w + acc[rr][7] + bb1.w);
    n_ = tanhf(g2.w + r_*(acc[rr][11] + bb2.w)); hv.w = (1.f-z_)*n_ + z_*hv.w;
    *(float4*)&h[(size_t)row*NH + jc] = hv;
  }
}

// ---- fused decoder step: gh GEMM + GRU + out-dot, pred chain
__global__ __launch_bounds__(512) void k_dec_fused(float* __restrict__ h,
    const float* __restrict__ BT, const float* __restrict__ dbhh,
    const float* __restrict__ ctxGX, const float* __restrict__ w0,
    const float* __restrict__ ow, const float* __restrict__ ob,
    float* __restrict__ pred, float* __restrict__ preds_out){
  __shared__ float As[16][68];
  __shared__ float Bs[16][388];
  int m0 = blockIdx.x*64;
  int tid = threadIdx.x, tx = tid & 31, ty = tid >> 5;
  float acc[4][12] = {};
  for (int k0=0; k0<NH; k0+=16){
    if (tid < 256){
      int r = tid & 63, kq = (tid >> 6)*4;
      float4 v = *(const float4*)&h[(size_t)(m0+r)*NH + k0 + kq];
      As[kq+0][r]=v.x; As[kq+1][r]=v.y; As[kq+2][r]=v.z; As[kq+3][r]=v.w;
    }
    {
      int kr = tid >> 5, cb = (tid & 31)*4;
      const float* bp = &BT[(size_t)(k0+kr)*384 + cb];
      *(float4*)&Bs[kr][cb]     = *(const float4*)(bp);
      *(float4*)&Bs[kr][cb+128] = *(const float4*)(bp+128);
      *(float4*)&Bs[kr][cb+256] = *(const float4*)(bp+256);
    }
    __syncthreads();
    #pragma unroll
    for (int kk=0;kk<16;++kk){
      float4 a = *(const float4*)&As[kk][ty*4];
      float4 b0 = *(const float4*)&Bs[kk][tx*4];
      float4 b1 = *(const float4*)&Bs[kk][tx*4+128];
      float4 b2 = *(const float4*)&Bs[kk][tx*4+256];
      float av[4] = {a.x,a.y,a.z,a.w};
      float bv[12] = {b0.x,b0.y,b0.z,b0.w,b1.x,b1.y,b1.z,b1.w,b2.x,b2.y,b2.z,b2.w};
      #pragma unroll
      for (int i=0;i<4;++i)
        #pragma unroll
        for (int j=0;j<12;++j) acc[i][j] += av[i]*bv[j];
    }
    __syncthreads();
  }
  int jc = tx*4;
  float4 bb0 = *(const float4*)&dbhh[jc];
  float4 bb1 = *(const float4*)&dbhh[jc+128];
  float4 bb2 = *(const float4*)&dbhh[jc+256];
  float4 w00 = *(const float4*)&w0[jc];
  float4 w01 = *(const float4*)&w0[jc+128];
  float4 w02 = *(const float4*)&w0[jc+256];
  float4 owv = *(const float4*)&ow[jc];
  float psum[4];
  #pragma unroll
  for (int rr=0;rr<4;++rr){
    int row = m0 + ty*4 + rr;
    float p = pred[row];
    const float* gx = ctxGX + (size_t)row*384 + jc;
    float4 g0 = *(const float4*)gx;
    float4 g1 = *(const float4*)(gx+128);
    float4 g2 = *(const float4*)(gx+256);
    float4 hv = *(float4*)&h[(size_t)row*NH + jc];
    float4 hn;
    float r_, z_, n_;
    r_ = sigf(g0.x + p*w00.x + acc[rr][0] + bb0.x); z_ = sigf(g1.x + p*w01.x + acc[rr][4] + bb1.x);
    n_ = tanhf(g2.x + p*w02.x + r_*(acc[rr][8] + bb2.x));  hn.x = (1.f-z_)*n_ + z_*hv.x;
    r_ = sigf(g0.y + p*w00.y + acc[rr][1] + bb0.y); z_ = sigf(g1.y + p*w01.y + acc[rr][5] + bb1.y);
    n_ = tanhf(g2.y + p*w02.y + r_*(acc[rr][9] + bb2.y));  hn.y = (1.f-z_)*n_ + z_*hv.y;
    r_ = sigf(g0.z + p*w00.z + acc[rr][2] + bb0.z); z_ = sigf(g1.z + p*w01.z + acc[rr][6] + bb1.z);
    n_ = tanhf(g2.z + p*w02.z + r_*(acc[rr][10] + bb2.z)); hn.z = (1.f-z_)*n_ + z_*hv.z;
    r_ = sigf(g0.w + p*w00.w + acc[rr][3] + bb0.w); z_ = sigf(g1.w + p*w01.w + acc[rr][7] + bb1.w);
    n_ = tanhf(g2.w + p*w02.w + r_*(acc[rr][11] + bb2.w)); hn.w = (1.f-z_)*n_ + z_*hv.w;
    *(float4*)&h[(size_t)row*NH + jc] = hn;
    psum[rr] = hn.x*owv.x + hn.y*owv.y + hn.z*owv.z + hn.w*owv.w;
  }
  #pragma unroll
  for (int off=16; off; off>>=1){
    #pragma unroll
    for (int rr=0;rr<4;++rr) psum[rr] += __shfl_xor(psum[rr], off, 64);
  }
  if (tx == 0){
    #pragma unroll
    for (int rr=0;rr<4;++rr){
      int row = m0 + ty*4 + rr;
      float pn = psum[rr] + ob[0];
      pred[row] = pn;
      preds_out[row] = pn;
    }
  }
}

// fusion, attn gate, write z in (tau, i, ZSTR) layout + ctx + pred0
__global__ __launch_bounds__(256) void k_zbuild(const float* __restrict__ x,
    const float* __restrict__ S, const float* __restrict__ cw, const float* __restrict__ cb,
    const float* __restrict__ aw, const float* __restrict__ ab,
    float* __restrict__ ztm, float* __restrict__ ctx, float* __restrict__ pred0){
  int tid = threadIdx.x;
  int rl = tid >> 6, l = tid & 63;
  int r = blockIdx.x*4 + rl;
  int n = r % NNODE, bt = r / NNODE, t = bt % NT, b = bt / NT;
  const float* xr = x + (size_t)r*NF;
  float fu, fu64 = 0.f;
  if (l == 0){
    fu = xr[0];
    float s_ = cb[31];
    #pragma unroll
    for (int f=0; f<13; ++f) s_ += xr[1+f]*cw[31*13+f];
    fu64 = s_ > 0.f ? s_ : 0.f;
  } else if (l < 33){
    fu = S[(size_t)(b*NNODE+n)*G3 + t*32 + (l-1)];
  } else {
    int o = l - 33;
    float s_ = cb[o];
    #pragma unroll
    for (int f=0; f<13; ++f) s_ += xr[1+f]*cw[o*13+f];
    fu = s_ > 0.f ? s_ : 0.f;
  }
  float part = fu*aw[l] + (l==0 ? fu64*aw[64] : 0.f);
  #pragma unroll
  for (int off=32; off; off>>=1) part += __shfl_down(part, off, 64);
  part = __shfl(part, 0, 64);
  float attn = sigf(part + ab[0]);
  int i_ = r / NT, tau = r % NT;          // scrambled reshape (B*N, T, 65)
  float* zr = ztm + ((size_t)tau*ROWS + i_)*ZSTR;
  zr[l] = fu*attn;
  if (l == 0) zr[64] = fu64*attn;         // pad cols 65..79 multiply zero weights
  if (t == NT-1){
    if (l >= 33) ctx[(size_t)(b*NNODE+n)*32 + (l-33)] = fu;
    if (l == 0){ ctx[(size_t)(b*NNODE+n)*32 + 31] = fu64; pred0[b*NNODE+n] = xr[0]; }
  }
}

__global__ __launch_bounds__(256) void k_out(const float* __restrict__ preds, float* __restrict__ out){
  int idx = blockIdx.x*256 + threadIdx.x;
  if (idx >= NT*ROWS) return;
  int n = idx % NNODE;
  int t2 = idx / NNODE;
  int hor = t2 % NT;
  int b = t2 / NT;
  out[idx] = preds[(size_t)hor*ROWS + b*NNODE + n];
}

extern "C" void kernel_launch(void* const* d_in, const int* in_sizes, int n_in,
                              void* d_out, int out_size, void* d_ws, size_t ws_size,
                              hipStream_t stream){
  const float* x     = (const float*)d_in[0];
  const float* Aph   = (const float*)d_in[1];
  const float* fcw   = (const float*)d_in[2];
  const float* fcb   = (const float*)d_in[3];
  const float* alp   = (const float*)d_in[4];
  const float* cw    = (const float*)d_in[5];
  const float* cb    = (const float*)d_in[6];
  const float* tw    = (const float*)d_in[7];
  const float* tb    = (const float*)d_in[8];
  const float* theta = (const float*)d_in[9];
  const float* aw    = (const float*)d_in[10];
  const float* ab    = (const float*)d_in[11];
  const float* ewih  = (const float*)d_in[12];
  const float* ewhh  = (const float*)d_in[13];
  const float* ebih  = (const float*)d_in[14];
  const float* ebhh  = (const float*)d_in[15];
  const float* dwih  = (const float*)d_in[16];
  const float* dwhh  = (const float*)d_in[17];
  const float* dbih  = (const float*)d_in[18];
  const float* dbhh  = (const float*)d_in[19];
  const float* ow    = (const float*)d_in[20];
  const float* ob    = (const float*)d_in[21];
  float* out = (float*)d_out;

  const size_t SZ_H    = (size_t)ROWS*NH;
  const size_t SZ_CTX  = (size_t)ROWS*32;
  const size_t SZ_PRED = (size_t)ROWS;
  const size_t SZ_PREDS= (size_t)NT*ROWS;
  const size_t SZ_G    = (size_t)ROWS*G3;
  const size_t SZ_ABUF = (size_t)NB*NNODE*LSTR;
  const size_t SZ_EMB  = (size_t)ROWS*16;
  const size_t SZ_Z    = (size_t)NT*ROWS*ZSTR;   // 25.4M >= 2*SZ_G

  float* w = (float*)d_ws;
  size_t off = 0;
  auto alloc = [&](size_t nfl){ float* p = w + off; off += nfl; return p; };
  float* h     = alloc(SZ_H);
  float* ctx   = alloc(SZ_CTX);
  float* pred  = alloc(SZ_PRED);
  float* preds = alloc(SZ_PREDS);
  float* Abuf  = alloc(SZ_ABUF);
  float* emb   = alloc(SZ_EMB);
  float* rsum  = alloc(SZ_PRED);
  float* lam   = alloc((size_t)NB);
  float* wt    = alloc((size_t)WT_TOTAL);
  float* Sslot = alloc(SZ_G);      // t_feat -> S -> gX -> ctxGX
  float* Zzone = alloc(SZ_Z);      // P1 | P2 ; later z (tau,i,ZSTR)
  float* P1 = Zzone;
  float* P2 = Zzone + SZ_G;
  (void)n_in; (void)in_sizes;

  if (ws_size < off*sizeof(float)){    // tripwire: workspace too small
    k_sentinel<<<(out_size+255)/256, 256, 0, stream>>>(out, out_size);
    return;
  }

  float* ewihT = wt + OFF_EWIHT;
  float* ewhhT = wt + OFF_EWHHT;
  float* dwhhT = wt + OFF_DWHHT;
  float* dwihT = wt + OFF_DWIHT;
  float* w0    = wt + OFF_W0;

  k_prep<<<(WT_TOTAL+255)/256, 256, 0, stream>>>(ewih, ewhh, dwih, dwhh, wt);
  float* tfeat = Sslot;
  k_emb<<<(ROWS*16)/256, 256, 0, stream>>>(x, fcw, fcb, emb);
  k_adj<<<ROWS/4, 256, 0, stream>>>(emb, Aph, alp, Abuf, rsum);
  k_lam<<<NB, 256, 0, stream>>>(rsum, lam);
  k_lap<<<(NB*NNODE*LSTR)/256, 256, 0, stream>>>(Abuf, lam);
  k_tcn<<<(BTN*32)/256, 256, 0, stream>>>(x, tw, tb, tfeat);
  k_thetaBC<<<BTN/8, 256, 0, stream>>>(tfeat, theta, P2, P1);
  // P2 <- 2*(L @ P1) + P2
  gemm128<<<dim3(3, 2, NB), 256, 0, stream>>>(Abuf, LSTR, (long long)NNODE*LSTR,
      P1, (long long)NNODE*G3, nullptr,
      P2, (long long)NNODE*G3, 2.f, 1.f, 0,
      P2, (long long)NNODE*G3, NNODE, 13);
  k_thetaA<<<BTN/8, 256, 0, stream>>>(tfeat, theta, P1);
  // Sslot <- relu((L @ P2) + P1)
  gemm128<<<dim3(3, 2, NB), 256, 0, stream>>>(Abuf, LSTR, (long long)NNODE*LSTR,
      P2, (long long)NNODE*G3, nullptr,
      P1, (long long)NNODE*G3, 1.f, 1.f, 1,
      Sslot, (long long)NNODE*G3, NNODE, 13);
  k_zbuild<<<BTN/4, 256, 0, stream>>>(x, Sslot, cw, cb, aw, ab, Zzone, ctx, pred);
  hipMemsetAsync(h, 0, SZ_H*sizeof(float), stream);

  float* gX = Sslot;   // S dead after zbuild
  for (int t=0; t<NT; ++t){
    gemm128<<<dim3(3, ROWS/128, 1), 256, 0, stream>>>(
        Zzone + (size_t)t*ROWS*ZSTR, ZSTR, 0, ewihT, 0, ebih,
        nullptr, 0, 1.f, 0.f, 0, gX, 0, ROWS, 5);
    k_enc_fused<<<ROWS/64, 512, 0, stream>>>(h, ewhhT, ebhh, gX);
  }
  float* ctxGX = Sslot;  // gX dead after encoder
  gemm128<<<dim3(3, ROWS/128, 1), 256, 0, stream>>>(
      ctx, 32, 0, dwihT, 0, dbih,
      nullptr, 0, 1.f, 0.f, 0, ctxGX, 0, ROWS, 2);
  for (int s=0; s<NT; ++s){
    k_dec_fused<<<ROWS/64, 512, 0, stream>>>(h, dwhhT, dbhh, ctxGX, w0, ow, ob,
        pred, preds + (size_t)s*ROWS);
  }
  k_out<<<(NT*ROWS)/256, 256, 0, stream>>>(preds, out);
}